// Round 1
// baseline (116.368 us; speedup 1.0000x reference)
//
#include <hip/hip_runtime.h>
#include <math.h>

// Problem constants (from reference)
#define B_  4
#define IC_ 3
#define OC_ 64
#define M_  4
#define KS_ 4
#define PAD_ 2
#define H_  128
#define W_  128
#define KK_ 16   // KS*KS

// Block: 256 threads = 4 oc-groups (16 oc each) x 64 w-lanes.
// Grid: B * H * (W/64) = 4*128*2 = 1024 blocks.
__global__ __launch_bounds__(256) void attn_stem_kernel(
    const float* __restrict__ x,       // (B,IC,H,W)
    const float* __restrict__ key_w,   // (OC,IC)
    const float* __restrict__ query_w, // (OC,IC)
    const float* __restrict__ value_w, // (M,OC,IC)
    const float* __restrict__ emb_a,   // (OC,KS)
    const float* __restrict__ emb_b,   // (OC,KS)
    const float* __restrict__ emb_mix, // (M,OC)
    float* __restrict__ out)           // (B,OC,H,W)
{
    __shared__ float s_embm[M_][KK_];        // softmaxed mixing weights
    __shared__ float s_weff[KK_ * OC_ * IC_]; // 3072 floats = 12 KB
    __shared__ float s_kw[OC_ * IC_];
    __shared__ float s_qw[OC_ * IC_];

    const int tid = threadIdx.x;

    // --- stage small weights into LDS ---
    if (tid < OC_ * IC_) {
        s_kw[tid] = key_w[tid];
        s_qw[tid] = query_w[tid];
    }

    // --- emb softmax: threads 0..15 each handle one window position k=(i,j) ---
    if (tid < KK_) {
        const int i = tid >> 2;
        const int j = tid & 3;
        float l[M_];
        #pragma unroll
        for (int m = 0; m < M_; ++m) {
            float la = 0.f, lb = 0.f;
            for (int c = 0; c < OC_; ++c) {
                const float emc = emb_mix[m * OC_ + c];
                la = fmaf(emc, emb_a[c * KS_ + i], la);
                lb = fmaf(emc, emb_b[c * KS_ + j], lb);
            }
            l[m] = la + lb;
        }
        float mx = fmaxf(fmaxf(l[0], l[1]), fmaxf(l[2], l[3]));
        float e0 = __expf(l[0] - mx);
        float e1 = __expf(l[1] - mx);
        float e2 = __expf(l[2] - mx);
        float e3 = __expf(l[3] - mx);
        const float inv = 1.f / (e0 + e1 + e2 + e3);
        s_embm[0][tid] = e0 * inv;
        s_embm[1][tid] = e1 * inv;
        s_embm[2][tid] = e2 * inv;
        s_embm[3][tid] = e3 * inv;
    }
    __syncthreads();

    // --- build Weff[k][o][c] = sum_m emb[m,k] * value_w[m,o,c] ---
    // 3072 entries / 256 threads = 12 each
    #pragma unroll
    for (int t = 0; t < 12; ++t) {
        const int e = tid * 12 + t;
        const int k = e / (OC_ * IC_);
        const int r = e - k * (OC_ * IC_);   // o*3+c
        float acc = 0.f;
        #pragma unroll
        for (int m = 0; m < M_; ++m)
            acc = fmaf(s_embm[m][k], value_w[m * OC_ * IC_ + r], acc);
        s_weff[e] = acc;
    }
    __syncthreads();

    // --- pixel mapping ---
    const int w0 = (blockIdx.x & 1) * 64;
    const int hb = blockIdx.x >> 1;
    const int h  = hb & (H_ - 1);
    const int b  = hb >> 7;
    const int w  = w0 + (tid & 63);
    const int g  = tid >> 6;           // oc-group 0..3

    // --- load 3x4x4 padded patch into registers (zero-fill = padding) ---
    float p[IC_][KK_];
    #pragma unroll
    for (int c = 0; c < IC_; ++c) {
        const float* __restrict__ xc = x + (((b * IC_ + c) << 7) << 7);
        #pragma unroll
        for (int i = 0; i < KS_; ++i) {
            const int hy = h + i - PAD_;
            const bool rok = (unsigned)hy < (unsigned)H_;
            #pragma unroll
            for (int j = 0; j < KS_; ++j) {
                const int wx = w + j - PAD_;
                const bool ok = rok && ((unsigned)wx < (unsigned)W_);
                p[c][i * KS_ + j] = ok ? xc[(hy << 7) + wx] : 0.f;
            }
        }
    }

    // --- per-oc attention ---
    const int obase = g * 16;
    #pragma unroll 2
    for (int oo = 0; oo < 16; ++oo) {
        const int o = obase + oo;
        const float qw0 = s_qw[o * 3 + 0], qw1 = s_qw[o * 3 + 1], qw2 = s_qw[o * 3 + 2];
        const float kw0 = s_kw[o * 3 + 0], kw1 = s_kw[o * 3 + 1], kw2 = s_kw[o * 3 + 2];
        // q uses unpadded center: padded offset (i=2,j=2) -> p[c][10]
        const float q = fmaf(qw0, p[0][10], fmaf(qw1, p[1][10], qw2 * p[2][10]));
        float num = 0.f, den = 0.f;
        #pragma unroll
        for (int k = 0; k < KK_; ++k) {
            const float kd = fmaf(kw0, p[0][k], fmaf(kw1, p[1][k], kw2 * p[2][k]));
            const float* wf = &s_weff[k * (OC_ * IC_) + o * 3];
            const float vs = fmaf(wf[0], p[0][k], fmaf(wf[1], p[1][k], wf[2] * p[2][k]));
            const float e = __expf(q * kd);
            num = fmaf(e, vs, num);
            den += e;
        }
        out[(((b * OC_ + o) << 7) + h) * W_ + w] = num / den;
    }
}

extern "C" void kernel_launch(void* const* d_in, const int* in_sizes, int n_in,
                              void* d_out, int out_size, void* d_ws, size_t ws_size,
                              hipStream_t stream) {
    const float* x       = (const float*)d_in[0];
    const float* key_w   = (const float*)d_in[1];
    const float* query_w = (const float*)d_in[2];
    const float* value_w = (const float*)d_in[3];
    const float* emb_a   = (const float*)d_in[4];
    const float* emb_b   = (const float*)d_in[5];
    const float* emb_mix = (const float*)d_in[6];
    float* out = (float*)d_out;

    const int grid = B_ * H_ * (W_ / 64);  // 1024
    attn_stem_kernel<<<grid, 256, 0, stream>>>(x, key_w, query_w, value_w,
                                               emb_a, emb_b, emb_mix, out);
}

// Round 2
// 101.112 us; speedup vs baseline: 1.1509x; 1.1509x over previous
//
#include <hip/hip_runtime.h>
#include <math.h>

// Problem constants (from reference)
#define B_  4
#define IC_ 3
#define OC_ 64
#define M_  4
#define KS_ 4
#define PAD_ 2
#define H_  128
#define W_  128
#define KK_ 16   // KS*KS

#if __has_builtin(__builtin_amdgcn_exp2f)
#define EXP2(x) __builtin_amdgcn_exp2f(x)
#else
#define EXP2(x) __expf((x) * 0.69314718055994531f)
#endif

// ---------------------------------------------------------------------------
// Kernel A: build the per-o weight record table in d_ws.
// wtab layout: 64 records of 64 floats. rec[0..2]=query_w[o], rec[3..5]=key_w[o],
// rec[6..7]=pad, rec[8+k*3+c] = Weff[k][o][c] = sum_m embm[m][k]*value_w[m][o][c].
// ---------------------------------------------------------------------------
__global__ __launch_bounds__(64) void attn_prep_kernel(
    const float* __restrict__ key_w,   // (OC,IC)
    const float* __restrict__ query_w, // (OC,IC)
    const float* __restrict__ value_w, // (M,OC,IC)
    const float* __restrict__ emb_a,   // (OC,KS)
    const float* __restrict__ emb_b,   // (OC,KS)
    const float* __restrict__ emb_mix, // (M,OC)
    float* __restrict__ wtab)          // (64,64)
{
    __shared__ float s_embm[M_][KK_];
    const int tid = threadIdx.x;

    if (tid < KK_) {
        const int i = tid >> 2;
        const int j = tid & 3;
        float l[M_];
        #pragma unroll
        for (int m = 0; m < M_; ++m) {
            float la = 0.f, lb = 0.f;
            for (int c = 0; c < OC_; ++c) {
                const float emc = emb_mix[m * OC_ + c];
                la = fmaf(emc, emb_a[c * KS_ + i], la);
                lb = fmaf(emc, emb_b[c * KS_ + j], lb);
            }
            l[m] = la + lb;
        }
        float mx = fmaxf(fmaxf(l[0], l[1]), fmaxf(l[2], l[3]));
        float e0 = __expf(l[0] - mx);
        float e1 = __expf(l[1] - mx);
        float e2 = __expf(l[2] - mx);
        float e3 = __expf(l[3] - mx);
        const float inv = 1.f / (e0 + e1 + e2 + e3);
        s_embm[0][tid] = e0 * inv;
        s_embm[1][tid] = e1 * inv;
        s_embm[2][tid] = e2 * inv;
        s_embm[3][tid] = e3 * inv;
    }
    __syncthreads();

    const int o = tid;  // 0..63
    float* rec = wtab + o * 64;
    rec[0] = query_w[o * 3 + 0];
    rec[1] = query_w[o * 3 + 1];
    rec[2] = query_w[o * 3 + 2];
    rec[3] = key_w[o * 3 + 0];
    rec[4] = key_w[o * 3 + 1];
    rec[5] = key_w[o * 3 + 2];
    rec[6] = 0.f;
    rec[7] = 0.f;
    #pragma unroll
    for (int k = 0; k < KK_; ++k) {
        #pragma unroll
        for (int c = 0; c < IC_; ++c) {
            float acc = 0.f;
            #pragma unroll
            for (int m = 0; m < M_; ++m)
                acc = fmaf(s_embm[m][k], value_w[(m * OC_ + o) * IC_ + c], acc);
            rec[8 + k * 3 + c] = acc;
        }
    }
}

// ---------------------------------------------------------------------------
// Kernel B: main attention. No LDS. Weights read through wave-uniform
// (readfirstlane-forced) addresses -> scalar s_load -> free SGPR operands.
// Grid 2048: (b, h, w-tile of 64, oc-half of 32). 256 thr = 4 groups x 64 lanes,
// each group handles 8 consecutive oc.
// ---------------------------------------------------------------------------
__global__ __launch_bounds__(256) void attn_main_kernel(
    const float* __restrict__ x,     // (B,IC,H,W)
    const float* __restrict__ wtab,  // (64,64)
    float* __restrict__ out)         // (B,OC,H,W)
{
    const int tid = threadIdx.x;
    const int bi  = blockIdx.x;
    const int wt  = bi & 1;          // w tile
    const int oh  = (bi >> 1) & 1;   // oc half
    const int h   = (bi >> 2) & (H_ - 1);
    const int b   = bi >> 9;
    const int w   = wt * 64 + (tid & 63);
    // wave-uniform oc base (tid>>6 is constant across a 64-lane wave)
    const int ob  = __builtin_amdgcn_readfirstlane(oh * 32 + (tid >> 6) * 8);

    // --- load 3x4x4 padded patch into registers (zero-fill = padding) ---
    float p[IC_][KK_];
    #pragma unroll
    for (int c = 0; c < IC_; ++c) {
        const float* __restrict__ xc = x + (((b * IC_ + c) << 7) << 7);
        #pragma unroll
        for (int i = 0; i < KS_; ++i) {
            const int hy = h + i - PAD_;
            const bool rok = (unsigned)hy < (unsigned)H_;
            #pragma unroll
            for (int j = 0; j < KS_; ++j) {
                const int wx = w + j - PAD_;
                const bool ok = rok && ((unsigned)wx < (unsigned)W_);
                p[c][i * KS_ + j] = ok ? xc[(hy << 7) + wx] : 0.f;
            }
        }
    }

    const float* __restrict__ recbase = wtab + ob * 64;  // uniform
    #pragma unroll
    for (int oo = 0; oo < 8; ++oo) {
        const float* __restrict__ rec = recbase + oo * 64;
        const float qw0 = rec[0], qw1 = rec[1], qw2 = rec[2];
        const float kw0 = rec[3], kw1 = rec[4], kw2 = rec[5];
        // q uses unpadded center: padded offset (i=2,j=2) -> p[c][10]
        const float q  = fmaf(qw0, p[0][10], fmaf(qw1, p[1][10], qw2 * p[2][10]));
        const float qs = q * 1.4426950408889634f;  // fold log2(e) once
        float num = 0.f, den = 0.f;
        #pragma unroll
        for (int k = 0; k < KK_; ++k) {
            const float kd = fmaf(kw0, p[0][k], fmaf(kw1, p[1][k], kw2 * p[2][k]));
            const float vs = fmaf(rec[8 + k * 3 + 0], p[0][k],
                             fmaf(rec[8 + k * 3 + 1], p[1][k],
                                  rec[8 + k * 3 + 2] * p[2][k]));
            const float e = EXP2(qs * kd);
            num = fmaf(e, vs, num);
            den += e;
        }
        const int o = ob + oo;
        out[((b * OC_ + o) << 14) + (h << 7) + w] = num * __builtin_amdgcn_rcpf(den);
    }
}

extern "C" void kernel_launch(void* const* d_in, const int* in_sizes, int n_in,
                              void* d_out, int out_size, void* d_ws, size_t ws_size,
                              hipStream_t stream) {
    const float* x       = (const float*)d_in[0];
    const float* key_w   = (const float*)d_in[1];
    const float* query_w = (const float*)d_in[2];
    const float* value_w = (const float*)d_in[3];
    const float* emb_a   = (const float*)d_in[4];
    const float* emb_b   = (const float*)d_in[5];
    const float* emb_mix = (const float*)d_in[6];
    float* wtab = (float*)d_ws;        // 64*64 floats = 16 KB
    float* out  = (float*)d_out;

    attn_prep_kernel<<<1, 64, 0, stream>>>(key_w, query_w, value_w,
                                           emb_a, emb_b, emb_mix, wtab);
    const int grid = B_ * H_ * 2 * 2;  // 2048
    attn_main_kernel<<<grid, 256, 0, stream>>>(x, wtab, out);
}

// Round 4
// 97.354 us; speedup vs baseline: 1.1953x; 1.0386x over previous
//
#include <hip/hip_runtime.h>
#include <math.h>
#include <stdint.h>

// Problem constants (from reference)
#define B_  4
#define IC_ 3
#define OC_ 64
#define M_  4
#define KS_ 4
#define PAD_ 2
#define H_  128
#define W_  128
#define KK_ 16            // KS*KS
#define PH_ 132           // H + 2*PAD
#define PW_ 132
#define PPLANE_ (PH_ * PW_)          // 17424 floats per (b,c) plane
#define NPAD_   (B_ * IC_ * PPLANE_) // 209088 padded elements
#define NPADBLK_ ((NPAD_ + 255) / 256)  // 817 pad blocks
#define WTAB_FLOATS_ 4096            // 64 records x 64 floats

#if __has_builtin(__builtin_amdgcn_exp2f)
#define EXP2(x) __builtin_amdgcn_exp2f(x)
#else
#define EXP2(x) __expf((x) * 0.69314718055994531f)
#endif

// 16-byte load with only 4-byte alignment guarantee (row starts are w-dependent)
struct __attribute__((packed, aligned(4))) F4 { float x0, x1, x2, x3; };

// constant address space -> guaranteed s_load for uniform addresses
typedef const __attribute__((address_space(4))) float cfloat;

// ---------------------------------------------------------------------------
// Prep kernel, grid = NPADBLK_+1.
// Blocks [0, NPADBLK_): zero-pad x into xpad (B,IC,132,132).
// Block NPADBLK_: build wtab: 64 records of 64 floats.
//   rec[0..2]=query_w[o], rec[3..5]=key_w[o], rec[6..7]=0,
//   rec[8+k*3+c] = Weff[k][o][c] = sum_m softmax_emb[m][k]*value_w[m][o][c].
// ---------------------------------------------------------------------------
__global__ __launch_bounds__(256) void attn_prep_kernel(
    const float* __restrict__ x,       // (B,IC,H,W)
    const float* __restrict__ key_w,   // (OC,IC)
    const float* __restrict__ query_w, // (OC,IC)
    const float* __restrict__ value_w, // (M,OC,IC)
    const float* __restrict__ emb_a,   // (OC,KS)
    const float* __restrict__ emb_b,   // (OC,KS)
    const float* __restrict__ emb_mix, // (M,OC)
    float* __restrict__ wtab,          // (64,64)
    float* __restrict__ xpad)          // (B,IC,132,132)
{
    const int tid = threadIdx.x;

    if (blockIdx.x < NPADBLK_) {
        const int idx = blockIdx.x * 256 + tid;
        if (idx < NPAD_) {
            const int plane = idx / PPLANE_;        // b*IC+c
            const int r     = idx - plane * PPLANE_;
            const int hy    = r / PW_;
            const int wx    = r - hy * PW_;
            const int hs = hy - PAD_;
            const int ws = wx - PAD_;
            float v = 0.f;
            if ((unsigned)hs < (unsigned)H_ && (unsigned)ws < (unsigned)W_)
                v = x[(plane << 14) + (hs << 7) + ws];
            xpad[idx] = v;
        }
        return;
    }

    // ---- weight block ----
    __shared__ float s_embm[M_][KK_];
    if (tid < KK_) {
        const int i = tid >> 2;
        const int j = tid & 3;
        float l[M_];
        #pragma unroll
        for (int m = 0; m < M_; ++m) {
            float la = 0.f, lb = 0.f;
            for (int c = 0; c < OC_; ++c) {
                const float emc = emb_mix[m * OC_ + c];
                la = fmaf(emc, emb_a[c * KS_ + i], la);
                lb = fmaf(emc, emb_b[c * KS_ + j], lb);
            }
            l[m] = la + lb;
        }
        float mx = fmaxf(fmaxf(l[0], l[1]), fmaxf(l[2], l[3]));
        float e0 = __expf(l[0] - mx);
        float e1 = __expf(l[1] - mx);
        float e2 = __expf(l[2] - mx);
        float e3 = __expf(l[3] - mx);
        const float inv = 1.f / (e0 + e1 + e2 + e3);
        s_embm[0][tid] = e0 * inv;
        s_embm[1][tid] = e1 * inv;
        s_embm[2][tid] = e2 * inv;
        s_embm[3][tid] = e3 * inv;
    }
    __syncthreads();

    if (tid < OC_) {
        const int o = tid;
        float* rec = wtab + o * 64;
        rec[0] = query_w[o * 3 + 0];
        rec[1] = query_w[o * 3 + 1];
        rec[2] = query_w[o * 3 + 2];
        rec[3] = key_w[o * 3 + 0];
        rec[4] = key_w[o * 3 + 1];
        rec[5] = key_w[o * 3 + 2];
        rec[6] = 0.f;
        rec[7] = 0.f;
        #pragma unroll
        for (int k = 0; k < KK_; ++k) {
            #pragma unroll
            for (int c = 0; c < IC_; ++c) {
                float acc = 0.f;
                #pragma unroll
                for (int m = 0; m < M_; ++m)
                    acc = fmaf(s_embm[m][k], value_w[(m * OC_ + o) * IC_ + c], acc);
                rec[8 + k * 3 + c] = acc;
            }
        }
    }
}

// ---------------------------------------------------------------------------
// Main kernel. Grid 2048 = (b, h, w-tile of 64, oc-half). 256 thr = 4 groups
// of 64 lanes; each group handles 8 consecutive oc. No LDS, no predication:
// 12 unconditional 16B patch loads from xpad; weights via addrspace(4)
// (forced s_load, free SGPR operands in the FMAs).
// ---------------------------------------------------------------------------
__global__ __launch_bounds__(256) void attn_main_kernel(
    const float* __restrict__ xpad,  // (B,IC,132,132)
    const float* __restrict__ wtab,  // (64,64)
    float* __restrict__ out)         // (B,OC,H,W)
{
    const int tid = threadIdx.x;
    const int bi  = blockIdx.x;
    const int wt  = bi & 1;          // w tile
    const int oh  = (bi >> 1) & 1;   // oc half
    const int h   = (bi >> 2) & (H_ - 1);
    const int b   = bi >> 9;
    const int w   = wt * 64 + (tid & 63);
    const int ob  = __builtin_amdgcn_readfirstlane(oh * 32 + (tid >> 6) * 8);

    // --- load 3x(4 rows of float4) padded patch, no bounds checks ---
    // then unpack to a plain register array p[c][i*4+j]
    float p[IC_][KK_];
    #pragma unroll
    for (int c = 0; c < IC_; ++c) {
        const float* rowp = xpad + (b * IC_ + c) * PPLANE_ + h * PW_ + w;
        #pragma unroll
        for (int i = 0; i < KS_; ++i) {
            const F4 v = *(const F4*)(rowp + i * PW_);
            p[c][i * 4 + 0] = v.x0;
            p[c][i * 4 + 1] = v.x1;
            p[c][i * 4 + 2] = v.x2;
            p[c][i * 4 + 3] = v.x3;
        }
    }

    cfloat* crec0 = (cfloat*)(uintptr_t)(wtab + ob * 64);

    #pragma unroll
    for (int oo = 0; oo < 8; ++oo) {
        cfloat* rec = crec0 + oo * 64;
        // q from unpadded center = padded (i=2, j=2) -> index 10; fold log2(e) into kw
        const float q  = fmaf(rec[0], p[0][10], fmaf(rec[1], p[1][10], rec[2] * p[2][10]));
        const float qs = q * 1.4426950408889634f;
        const float kws0 = rec[3] * qs;
        const float kws1 = rec[4] * qs;
        const float kws2 = rec[5] * qs;
        float num = 0.f, den = 0.f;
        #pragma unroll
        for (int k = 0; k < KK_; ++k) {
            const float a0 = p[0][k], a1 = p[1][k], a2 = p[2][k];
            const float t  = fmaf(kws0, a0, fmaf(kws1, a1, kws2 * a2));
            const float e  = EXP2(t);
            const float vs = fmaf(rec[8 + k*3 + 0], a0,
                              fmaf(rec[8 + k*3 + 1], a1,
                                   rec[8 + k*3 + 2] * a2));
            num = fmaf(e, vs, num);
            den += e;
        }
        out[((b * OC_ + ob + oo) << 14) + (h << 7) + w] = num * __builtin_amdgcn_rcpf(den);
    }
}

extern "C" void kernel_launch(void* const* d_in, const int* in_sizes, int n_in,
                              void* d_out, int out_size, void* d_ws, size_t ws_size,
                              hipStream_t stream) {
    const float* x       = (const float*)d_in[0];
    const float* key_w   = (const float*)d_in[1];
    const float* query_w = (const float*)d_in[2];
    const float* value_w = (const float*)d_in[3];
    const float* emb_a   = (const float*)d_in[4];
    const float* emb_b   = (const float*)d_in[5];
    const float* emb_mix = (const float*)d_in[6];
    float* wtab = (float*)d_ws;                    // 4096 floats = 16 KB
    float* xpad = (float*)d_ws + WTAB_FLOATS_;     // 209088 floats = 836 KB
    float* out  = (float*)d_out;

    attn_prep_kernel<<<NPADBLK_ + 1, 256, 0, stream>>>(
        x, key_w, query_w, value_w, emb_a, emb_b, emb_mix, wtab, xpad);
    attn_main_kernel<<<B_ * H_ * 2 * 2, 256, 0, stream>>>(xpad, wtab, out);
}

// Round 5
// 92.374 us; speedup vs baseline: 1.2598x; 1.0539x over previous
//
#include <hip/hip_runtime.h>
#include <math.h>
#include <stdint.h>

// Problem constants (from reference)
#define B_  4
#define IC_ 3
#define OC_ 64
#define M_  4
#define KS_ 4
#define PAD_ 2
#define H_  128
#define W_  128
#define KK_ 16            // KS*KS
#define PH_ 132           // H + 2*PAD
#define PW_ 132
#define PPLANE_ (PH_ * PW_)          // 17424 floats per (b,c) plane
#define NPAD_   (B_ * IC_ * PPLANE_) // 209088 padded elements
#define NPADBLK_ ((NPAD_ + 255) / 256)  // 817 pad blocks
#define WTAB_FLOATS_ 4096            // 64 records x 64 floats

#if __has_builtin(__builtin_amdgcn_exp2f)
#define EXP2(x) __builtin_amdgcn_exp2f(x)
#else
#define EXP2(x) __expf((x) * 0.69314718055994531f)
#endif

typedef float v2f __attribute__((ext_vector_type(2)));

// 16-byte load with only 4-byte alignment guarantee (row starts are w-dependent)
struct __attribute__((packed, aligned(4))) F4 { float x0, x1, x2, x3; };

// constant address space -> guaranteed s_load for uniform addresses
typedef const __attribute__((address_space(4))) float cfloat;

// ---------------------------------------------------------------------------
// Prep kernel, grid = NPADBLK_+1.
// Blocks [0, NPADBLK_): zero-pad x into xpad (B,IC,132,132).
// Block NPADBLK_: build wtab, 64 records of 64 floats (SoA for pk pairs):
//   rec[0..2]=query_w[o], rec[3..5]=key_w[o], rec[6..7]=0,
//   rec[ 8+k]=Weff[k][o][0], rec[24+k]=Weff[k][o][1], rec[40+k]=Weff[k][o][2]
//   (k = 0..15), rec[56..63]=0.
// ---------------------------------------------------------------------------
__global__ __launch_bounds__(256) void attn_prep_kernel(
    const float* __restrict__ x,       // (B,IC,H,W)
    const float* __restrict__ key_w,   // (OC,IC)
    const float* __restrict__ query_w, // (OC,IC)
    const float* __restrict__ value_w, // (M,OC,IC)
    const float* __restrict__ emb_a,   // (OC,KS)
    const float* __restrict__ emb_b,   // (OC,KS)
    const float* __restrict__ emb_mix, // (M,OC)
    float* __restrict__ wtab,          // (64,64)
    float* __restrict__ xpad)          // (B,IC,132,132)
{
    const int tid = threadIdx.x;

    if (blockIdx.x < NPADBLK_) {
        const int idx = blockIdx.x * 256 + tid;
        if (idx < NPAD_) {
            const int plane = idx / PPLANE_;        // b*IC+c
            const int r     = idx - plane * PPLANE_;
            const int hy    = r / PW_;
            const int wx    = r - hy * PW_;
            const int hs = hy - PAD_;
            const int ws = wx - PAD_;
            float v = 0.f;
            if ((unsigned)hs < (unsigned)H_ && (unsigned)ws < (unsigned)W_)
                v = x[(plane << 14) + (hs << 7) + ws];
            xpad[idx] = v;
        }
        return;
    }

    // ---- weight block ----
    __shared__ float s_embm[M_][KK_];
    if (tid < KK_) {
        const int i = tid >> 2;
        const int j = tid & 3;
        float l[M_];
        #pragma unroll
        for (int m = 0; m < M_; ++m) {
            float la = 0.f, lb = 0.f;
            for (int c = 0; c < OC_; ++c) {
                const float emc = emb_mix[m * OC_ + c];
                la = fmaf(emc, emb_a[c * KS_ + i], la);
                lb = fmaf(emc, emb_b[c * KS_ + j], lb);
            }
            l[m] = la + lb;
        }
        float mx = fmaxf(fmaxf(l[0], l[1]), fmaxf(l[2], l[3]));
        float e0 = __expf(l[0] - mx);
        float e1 = __expf(l[1] - mx);
        float e2 = __expf(l[2] - mx);
        float e3 = __expf(l[3] - mx);
        const float inv = 1.f / (e0 + e1 + e2 + e3);
        s_embm[0][tid] = e0 * inv;
        s_embm[1][tid] = e1 * inv;
        s_embm[2][tid] = e2 * inv;
        s_embm[3][tid] = e3 * inv;
    }
    __syncthreads();

    if (tid < OC_) {
        const int o = tid;
        float* rec = wtab + o * 64;
        rec[0] = query_w[o * 3 + 0];
        rec[1] = query_w[o * 3 + 1];
        rec[2] = query_w[o * 3 + 2];
        rec[3] = key_w[o * 3 + 0];
        rec[4] = key_w[o * 3 + 1];
        rec[5] = key_w[o * 3 + 2];
        rec[6] = 0.f;
        rec[7] = 0.f;
        #pragma unroll
        for (int k = 0; k < KK_; ++k) {
            #pragma unroll
            for (int c = 0; c < IC_; ++c) {
                float acc = 0.f;
                #pragma unroll
                for (int m = 0; m < M_; ++m)
                    acc = fmaf(s_embm[m][k], value_w[(m * OC_ + o) * IC_ + c], acc);
                rec[8 + c * 16 + k] = acc;
            }
        }
        rec[56] = rec[57] = rec[58] = rec[59] = 0.f;
        rec[60] = rec[61] = rec[62] = rec[63] = 0.f;
    }
}

// ---------------------------------------------------------------------------
// Main kernel. Grid 2048 = (b, h, w-tile of 64, oc-half). 256 thr = 4 wave
// groups; each group handles 8 consecutive oc. No LDS, no predication.
// Inner loop processes k in PAIRS via float2 ext-vectors -> v_pk_fma_f32.
// Weights via addrspace(4) (s_load, SGPR operands).
// ---------------------------------------------------------------------------
__global__ __launch_bounds__(256) void attn_main_kernel(
    const float* __restrict__ xpad,  // (B,IC,132,132)
    const float* __restrict__ wtab,  // (64,64)
    float* __restrict__ out)         // (B,OC,H,W)
{
    const int tid = threadIdx.x;
    const int bi  = blockIdx.x;
    const int wt  = bi & 1;          // w tile
    const int oh  = (bi >> 1) & 1;   // oc half
    const int h   = (bi >> 2) & (H_ - 1);
    const int b   = bi >> 9;
    const int w   = wt * 64 + (tid & 63);
    const int ob  = __builtin_amdgcn_readfirstlane(oh * 32 + (tid >> 6) * 8);

    // --- load 3x(4 rows of float4) padded patch, pack as k-pairs ---
    // pp[c][kp] = (patch[c][2kp], patch[c][2kp+1]),  k = i*4+j
    v2f pp[IC_][8];
    #pragma unroll
    for (int c = 0; c < IC_; ++c) {
        const float* rowp = xpad + (b * IC_ + c) * PPLANE_ + h * PW_ + w;
        #pragma unroll
        for (int i = 0; i < KS_; ++i) {
            const F4 v = *(const F4*)(rowp + i * PW_);
            pp[c][i * 2 + 0] = (v2f){v.x0, v.x1};
            pp[c][i * 2 + 1] = (v2f){v.x2, v.x3};
        }
    }

    cfloat* crec0 = (cfloat*)(uintptr_t)(wtab + ob * 64);

    #pragma unroll
    for (int oo = 0; oo < 8; ++oo) {
        cfloat* rec = crec0 + oo * 64;
        // q from unpadded center = padded k=10 -> pair 5, lo half
        const float q  = fmaf(rec[0], pp[0][5].x,
                         fmaf(rec[1], pp[1][5].x, rec[2] * pp[2][5].x));
        const float qs = q * 1.4426950408889634f;   // fold log2(e)
        const float kws0 = rec[3] * qs;
        const float kws1 = rec[4] * qs;
        const float kws2 = rec[5] * qs;
        v2f numv = (v2f){0.f, 0.f};
        v2f denv = (v2f){0.f, 0.f};
        #pragma unroll
        for (int kp = 0; kp < 8; ++kp) {
            const v2f a0 = pp[0][kp], a1 = pp[1][kp], a2 = pp[2][kp];
            v2f t = kws0 * a0 + kws1 * a1 + kws2 * a2;        // pk fma chain
            v2f ev;
            ev.x = EXP2(t.x);
            ev.y = EXP2(t.y);
            const v2f w0 = (v2f){rec[ 8 + 2*kp], rec[ 9 + 2*kp]};
            const v2f w1 = (v2f){rec[24 + 2*kp], rec[25 + 2*kp]};
            const v2f w2 = (v2f){rec[40 + 2*kp], rec[41 + 2*kp]};
            v2f vs = w0 * a0 + w1 * a1 + w2 * a2;             // pk fma chain
            numv = ev * vs + numv;                            // pk fma
            denv = denv + ev;                                 // pk add
        }
        const float num = numv.x + numv.y;
        const float den = denv.x + denv.y;
        out[((b * OC_ + ob + oo) << 14) + (h << 7) + w] =
            num * __builtin_amdgcn_rcpf(den);
    }
}

extern "C" void kernel_launch(void* const* d_in, const int* in_sizes, int n_in,
                              void* d_out, int out_size, void* d_ws, size_t ws_size,
                              hipStream_t stream) {
    const float* x       = (const float*)d_in[0];
    const float* key_w   = (const float*)d_in[1];
    const float* query_w = (const float*)d_in[2];
    const float* value_w = (const float*)d_in[3];
    const float* emb_a   = (const float*)d_in[4];
    const float* emb_b   = (const float*)d_in[5];
    const float* emb_mix = (const float*)d_in[6];
    float* wtab = (float*)d_ws;                    // 4096 floats = 16 KB
    float* xpad = (float*)d_ws + WTAB_FLOATS_;     // 209088 floats = 836 KB
    float* out  = (float*)d_out;

    attn_prep_kernel<<<NPADBLK_ + 1, 256, 0, stream>>>(
        x, key_w, query_w, value_w, emb_a, emb_b, emb_mix, wtab, xpad);
    attn_main_kernel<<<B_ * H_ * 2 * 2, 256, 0, stream>>>(xpad, wtab, out);
}

// Round 6
// 86.837 us; speedup vs baseline: 1.3401x; 1.0638x over previous
//
#include <hip/hip_runtime.h>
#include <math.h>
#include <stdint.h>

// Problem constants (from reference)
#define B_  4
#define IC_ 3
#define OC_ 64
#define M_  4
#define KS_ 4
#define PAD_ 2
#define H_  128
#define W_  128
#define KK_ 16            // KS*KS
#define PH_ 132           // H + 2*PAD
#define PW_ 132
#define PPLANE_ (PH_ * PW_)          // 17424 floats per (b,c) plane
#define NPAD_   (B_ * IC_ * PPLANE_) // 209088 padded elements
#define NPADBLK_ ((NPAD_ + 255) / 256)  // 817 pad blocks
#define WTAB_FLOATS_ 4096            // 64 records x 64 floats

#if __has_builtin(__builtin_amdgcn_exp2f)
#define EXP2(x) __builtin_amdgcn_exp2f(x)
#else
#define EXP2(x) __expf((x) * 0.69314718055994531f)
#endif

typedef float v2f __attribute__((ext_vector_type(2)));

// 16-byte load with only 4-byte alignment guarantee (row starts are w-dependent)
struct __attribute__((packed, aligned(4))) F4 { float x0, x1, x2, x3; };

// constant address space -> guaranteed s_load for uniform addresses
typedef const __attribute__((address_space(4))) float cfloat;

// ---------------------------------------------------------------------------
// Prep kernel, grid = NPADBLK_+1.
// Blocks [0, NPADBLK_): zero-pad x into xpad (B,IC,132,132).
// Block NPADBLK_: build wtab, 64 records of 64 floats (SoA for pk pairs):
//   rec[0..2]=query_w[o], rec[3..5]=key_w[o], rec[6..7]=0,
//   rec[ 8+k]=Weff[k][o][0], rec[24+k]=Weff[k][o][1], rec[40+k]=Weff[k][o][2]
//   (k = 0..15), rec[56..63]=0.
// The emb logits are computed wave-parallel: wave m, lane c -> shfl reduce.
// ---------------------------------------------------------------------------
__global__ __launch_bounds__(256) void attn_prep_kernel(
    const float* __restrict__ x,       // (B,IC,H,W)
    const float* __restrict__ key_w,   // (OC,IC)
    const float* __restrict__ query_w, // (OC,IC)
    const float* __restrict__ value_w, // (M,OC,IC)
    const float* __restrict__ emb_a,   // (OC,KS)
    const float* __restrict__ emb_b,   // (OC,KS)
    const float* __restrict__ emb_mix, // (M,OC)
    float* __restrict__ wtab,          // (64,64)
    float* __restrict__ xpad)          // (B,IC,132,132)
{
    const int tid = threadIdx.x;

    if (blockIdx.x < NPADBLK_) {
        const int idx = blockIdx.x * 256 + tid;
        if (idx < NPAD_) {
            const int plane = idx / PPLANE_;        // b*IC+c
            const int r     = idx - plane * PPLANE_;
            const int hy    = r / PW_;
            const int wx    = r - hy * PW_;
            const int hs = hy - PAD_;
            const int ws = wx - PAD_;
            float v = 0.f;
            if ((unsigned)hs < (unsigned)H_ && (unsigned)ws < (unsigned)W_)
                v = x[(plane << 14) + (hs << 7) + ws];
            xpad[idx] = v;
        }
        return;
    }

    // ---- weight block ----
    // Wave-parallel logits: wave = m (4 waves), lane = c (64 lanes).
    __shared__ float s_l[M_][8];     // la[i] (r=0..3), lb[j] (r=4..7) per m
    __shared__ float s_embm[M_][KK_];

    {
        const int m = tid >> 6;
        const int c = tid & 63;
        const float emc = emb_mix[m * OC_ + c];
        float red[8];
        #pragma unroll
        for (int i = 0; i < KS_; ++i) {
            red[i]     = emc * emb_a[c * KS_ + i];
            red[4 + i] = emc * emb_b[c * KS_ + i];
        }
        #pragma unroll
        for (int off = 32; off; off >>= 1) {
            #pragma unroll
            for (int r = 0; r < 8; ++r)
                red[r] += __shfl_down(red[r], off);
        }
        if (c == 0) {
            #pragma unroll
            for (int r = 0; r < 8; ++r)
                s_l[m][r] = red[r];
        }
    }
    __syncthreads();

    if (tid < KK_) {
        const int i = tid >> 2;
        const int j = tid & 3;
        float l[M_];
        #pragma unroll
        for (int m = 0; m < M_; ++m)
            l[m] = s_l[m][i] + s_l[m][4 + j];
        float mx = fmaxf(fmaxf(l[0], l[1]), fmaxf(l[2], l[3]));
        float e0 = __expf(l[0] - mx);
        float e1 = __expf(l[1] - mx);
        float e2 = __expf(l[2] - mx);
        float e3 = __expf(l[3] - mx);
        const float inv = 1.f / (e0 + e1 + e2 + e3);
        s_embm[0][tid] = e0 * inv;
        s_embm[1][tid] = e1 * inv;
        s_embm[2][tid] = e2 * inv;
        s_embm[3][tid] = e3 * inv;
    }
    __syncthreads();

    if (tid < OC_) {
        const int o = tid;
        float* rec = wtab + o * 64;
        rec[0] = query_w[o * 3 + 0];
        rec[1] = query_w[o * 3 + 1];
        rec[2] = query_w[o * 3 + 2];
        rec[3] = key_w[o * 3 + 0];
        rec[4] = key_w[o * 3 + 1];
        rec[5] = key_w[o * 3 + 2];
        rec[6] = 0.f;
        rec[7] = 0.f;
        #pragma unroll
        for (int k = 0; k < KK_; ++k) {
            #pragma unroll
            for (int c = 0; c < IC_; ++c) {
                float acc = 0.f;
                #pragma unroll
                for (int m = 0; m < M_; ++m)
                    acc = fmaf(s_embm[m][k], value_w[(m * OC_ + o) * IC_ + c], acc);
                rec[8 + c * 16 + k] = acc;
            }
        }
        rec[56] = rec[57] = rec[58] = rec[59] = 0.f;
        rec[60] = rec[61] = rec[62] = rec[63] = 0.f;
    }
}

// ---------------------------------------------------------------------------
// Main kernel. Grid 2048 = (b, h, w-tile of 64, oc-half). 256 thr = 4 wave
// groups; each group handles 8 consecutive oc. No LDS, no predication.
// k processed in pairs via float2 -> v_pk_fma_f32; weights via addrspace(4).
// __launch_bounds__(256, 8): force VGPR<=64 so all 8 waves/SIMD are resident
// (occupancy experiment — prior full unroll likely inflated VGPRs).
// #pragma unroll 2 keeps per-iteration register footprint small while still
// letting the scheduler overlap s_loads of oo+1 with compute of oo.
// ---------------------------------------------------------------------------
__global__ __launch_bounds__(256, 8) void attn_main_kernel(
    const float* __restrict__ xpad,  // (B,IC,132,132)
    const float* __restrict__ wtab,  // (64,64)
    float* __restrict__ out)         // (B,OC,H,W)
{
    const int tid = threadIdx.x;
    const int bi  = blockIdx.x;
    const int wt  = bi & 1;          // w tile
    const int oh  = (bi >> 1) & 1;   // oc half
    const int h   = (bi >> 2) & (H_ - 1);
    const int b   = bi >> 9;
    const int w   = wt * 64 + (tid & 63);
    const int ob  = __builtin_amdgcn_readfirstlane(oh * 32 + (tid >> 6) * 8);

    // --- load 3x(4 rows of float4) padded patch, pack as k-pairs ---
    // pp[c][kp] = (patch[c][2kp], patch[c][2kp+1]),  k = i*4+j
    v2f pp[IC_][8];
    #pragma unroll
    for (int c = 0; c < IC_; ++c) {
        const float* rowp = xpad + (b * IC_ + c) * PPLANE_ + h * PW_ + w;
        #pragma unroll
        for (int i = 0; i < KS_; ++i) {
            const F4 v = *(const F4*)(rowp + i * PW_);
            pp[c][i * 2 + 0] = (v2f){v.x0, v.x1};
            pp[c][i * 2 + 1] = (v2f){v.x2, v.x3};
        }
    }

    cfloat* crec0 = (cfloat*)(uintptr_t)(wtab + ob * 64);

    #pragma unroll 2
    for (int oo = 0; oo < 8; ++oo) {
        cfloat* rec = crec0 + oo * 64;
        // q from unpadded center = padded k=10 -> pair 5, lo half
        const float q  = fmaf(rec[0], pp[0][5].x,
                         fmaf(rec[1], pp[1][5].x, rec[2] * pp[2][5].x));
        const float qs = q * 1.4426950408889634f;   // fold log2(e)
        const float kws0 = rec[3] * qs;
        const float kws1 = rec[4] * qs;
        const float kws2 = rec[5] * qs;
        v2f numv = (v2f){0.f, 0.f};
        v2f denv = (v2f){0.f, 0.f};
        #pragma unroll
        for (int kp = 0; kp < 8; ++kp) {
            const v2f a0 = pp[0][kp], a1 = pp[1][kp], a2 = pp[2][kp];
            v2f t = kws0 * a0 + kws1 * a1 + kws2 * a2;        // pk fma chain
            v2f ev;
            ev.x = EXP2(t.x);
            ev.y = EXP2(t.y);
            const v2f w0 = (v2f){rec[ 8 + 2*kp], rec[ 9 + 2*kp]};
            const v2f w1 = (v2f){rec[24 + 2*kp], rec[25 + 2*kp]};
            const v2f w2 = (v2f){rec[40 + 2*kp], rec[41 + 2*kp]};
            v2f vs = w0 * a0 + w1 * a1 + w2 * a2;             // pk fma chain
            numv = ev * vs + numv;                            // pk fma
            denv = denv + ev;                                 // pk add
        }
        const float num = numv.x + numv.y;
        const float den = denv.x + denv.y;
        out[((b * OC_ + ob + oo) << 14) + (h << 7) + w] =
            num * __builtin_amdgcn_rcpf(den);
    }
}

extern "C" void kernel_launch(void* const* d_in, const int* in_sizes, int n_in,
                              void* d_out, int out_size, void* d_ws, size_t ws_size,
                              hipStream_t stream) {
    const float* x       = (const float*)d_in[0];
    const float* key_w   = (const float*)d_in[1];
    const float* query_w = (const float*)d_in[2];
    const float* value_w = (const float*)d_in[3];
    const float* emb_a   = (const float*)d_in[4];
    const float* emb_b   = (const float*)d_in[5];
    const float* emb_mix = (const float*)d_in[6];
    float* wtab = (float*)d_ws;                    // 4096 floats = 16 KB
    float* xpad = (float*)d_ws + WTAB_FLOATS_;     // 209088 floats = 836 KB
    float* out  = (float*)d_out;

    attn_prep_kernel<<<NPADBLK_ + 1, 256, 0, stream>>>(
        x, key_w, query_w, value_w, emb_a, emb_b, emb_mix, wtab, xpad);
    attn_main_kernel<<<B_ * H_ * 2 * 2, 256, 0, stream>>>(xpad, wtab, out);
}